// Round 1
// baseline (1916.563 us; speedup 1.0000x reference)
//
#include <hip/hip_runtime.h>

#define PFD 4   // prefetch distance (slots statically indexed via unrolled loop)

constexpr int Bv = 2, Tv = 4096, Hv = 8, Kv = 64, Vv = 64;

__global__ __launch_bounds__(64, 1)
void gdr1dc_kernel(const float* __restrict__ qg, const float* __restrict__ kg,
                   const float* __restrict__ vg, const float* __restrict__ gg,
                   const float* __restrict__ bg, const float* __restrict__ lqg,
                   const float* __restrict__ lkg, const float* __restrict__ S0,
                   const float* __restrict__ b0,
                   float* __restrict__ o_out, float* __restrict__ S_out,
                   float* __restrict__ b_out)
{
    const int bid  = blockIdx.x;
    const int bh   = bid >> 2;        // b*H + h
    const int cg   = bid & 3;         // which group of 16 output columns
    const int lane = threadIdx.x;     // 0..63
    const int ksub = lane >> 4;       // 0..3 : which 16-slice of K this lane owns
    const int c    = lane & 15;       // 0..15 : column within group
    const int col  = cg * 16 + c;     // output column v in [0,64)

    __shared__ __align__(16) float lds_k[64];
    __shared__ __align__(16) float lds_q[64];

    // state: this lane owns S[ksub*16 + j][col], j = 0..15
    float S[16];
#pragma unroll
    for (int j = 0; j < 16; ++j)
        S[j] = S0[((size_t)bh * Kv + (ksub * 16 + j)) * Vv + col];
    float bv = b0[(size_t)bh * Vv + col];   // replicated across the 4 ksub lanes

    const int b = bh / Hv, h = bh % Hv;
    const size_t t0 = (size_t)b * Tv * Hv + h;   // flat [b,t=0,h] index

    // prefetch pipeline registers
    float kr[PFD], qr[PFD], vr[PFD], gr[PFD], br[PFD], lqr[PFD], lkr[PFD];
#pragma unroll
    for (int p = 0; p < PFD; ++p) {
        size_t i3 = t0 + (size_t)p * Hv;
        kr[p] = kg[i3 * Kv + lane];
        qr[p] = qg[i3 * Kv + lane];
        vr[p] = vg[i3 * Vv + col];
        gr[p] = gg[i3]; br[p] = bg[i3]; lqr[p] = lqg[i3]; lkr[p] = lkg[i3];
    }

    for (int tt = 0; tt < Tv; tt += PFD) {
#pragma unroll
        for (int s = 0; s < PFD; ++s) {   // s is compile-time after unroll
            const int t = tt + s;

            // stage k_t, q_t to LDS (single wave: in-order LDS, no barrier)
            lds_k[lane] = kr[s];
            lds_q[lane] = qr[s];
            const float vt  = vr[s];
            const float dec = __expf(gr[s]);
            const float bt  = br[s];
            const float lqt = lqr[s], lkt = lkr[s];

            const float4* kf = (const float4*)lds_k;
            float4 k0 = kf[ksub*4+0], k1 = kf[ksub*4+1],
                   k2 = kf[ksub*4+2], k3 = kf[ksub*4+3];
            float ka[16] = {k0.x,k0.y,k0.z,k0.w, k1.x,k1.y,k1.z,k1.w,
                            k2.x,k2.y,k2.z,k2.w, k3.x,k3.y,k3.z,k3.w};

            // v_pred partial over this lane's 16 K-rows (4 independent chains)
            float a0 = 0.f, a1 = 0.f, a2 = 0.f, a3 = 0.f;
#pragma unroll
            for (int j = 0; j < 4; ++j) {
                a0 = fmaf(ka[4*j+0], S[4*j+0], a0);
                a1 = fmaf(ka[4*j+1], S[4*j+1], a1);
                a2 = fmaf(ka[4*j+2], S[4*j+2], a2);
                a3 = fmaf(ka[4*j+3], S[4*j+3], a3);
            }
            float vp = (a0 + a1) + (a2 + a3);
            vp += __shfl_xor(vp, 16);      // reduce over the 4 ksub lanes
            vp += __shfl_xor(vp, 32);
            vp  = dec * fmaf(lkt, bv, vp); // = k·(dec·S) + lk·(dec·b)
            const float u = bt * (vt - vp);

            // state update: S = dec*S + k⊗u   (pre-decay folded here)
#pragma unroll
            for (int j = 0; j < 16; ++j)
                S[j] = fmaf(ka[j], u, dec * S[j]);
            bv = fmaf(lkt, u, dec * bv);

            // output dot with updated state
            const float4* qf = (const float4*)lds_q;
            float4 q0 = qf[ksub*4+0], q1 = qf[ksub*4+1],
                   q2 = qf[ksub*4+2], q3 = qf[ksub*4+3];
            float qa[16] = {q0.x,q0.y,q0.z,q0.w, q1.x,q1.y,q1.z,q1.w,
                            q2.x,q2.y,q2.z,q2.w, q3.x,q3.y,q3.z,q3.w};
            float o0 = 0.f, o1 = 0.f, o2 = 0.f, o3 = 0.f;
#pragma unroll
            for (int j = 0; j < 4; ++j) {
                o0 = fmaf(qa[4*j+0], S[4*j+0], o0);
                o1 = fmaf(qa[4*j+1], S[4*j+1], o1);
                o2 = fmaf(qa[4*j+2], S[4*j+2], o2);
                o3 = fmaf(qa[4*j+3], S[4*j+3], o3);
            }
            float od = (o0 + o1) + (o2 + o3);
            od += __shfl_xor(od, 16);
            od += __shfl_xor(od, 32);
            const float o = fmaf(0.125f, od, lqt * bv);
            if (ksub == 0)
                o_out[(t0 + (size_t)t * Hv) * Vv + col] = o;

            // prefetch step t+PFD into this slot (clamped; dup loads harmless)
            {
                int tn = t + PFD; if (tn >= Tv) tn = Tv - 1;
                size_t i3 = t0 + (size_t)tn * Hv;
                kr[s] = kg[i3 * Kv + lane];
                qr[s] = qg[i3 * Kv + lane];
                vr[s] = vg[i3 * Vv + col];
                gr[s] = gg[i3]; br[s] = bg[i3]; lqr[s] = lqg[i3]; lkr[s] = lkg[i3];
            }
        }
    }

    // final state outputs
#pragma unroll
    for (int j = 0; j < 16; ++j)
        S_out[((size_t)bh * Kv + (ksub * 16 + j)) * Vv + col] = S[j];
    if (ksub == 0)
        b_out[(size_t)bh * Vv + col] = bv;
}

extern "C" void kernel_launch(void* const* d_in, const int* in_sizes, int n_in,
                              void* d_out, int out_size, void* d_ws, size_t ws_size,
                              hipStream_t stream) {
    const float* q   = (const float*)d_in[0];
    const float* k   = (const float*)d_in[1];
    const float* v   = (const float*)d_in[2];
    const float* g   = (const float*)d_in[3];
    const float* bet = (const float*)d_in[4];
    const float* lq  = (const float*)d_in[5];
    const float* lk  = (const float*)d_in[6];
    const float* S0  = (const float*)d_in[7];
    const float* b0  = (const float*)d_in[8];

    float* out   = (float*)d_out;
    float* o_out = out;
    float* S_out = out + (size_t)Bv * Tv * Hv * Vv;
    float* b_out = S_out + (size_t)Bv * Hv * Kv * Vv;

    dim3 grid(Bv * Hv * 4);   // 4 column-groups per (b,h)
    dim3 block(64);
    gdr1dc_kernel<<<grid, block, 0, stream>>>(q, k, v, g, bet, lq, lk, S0, b0,
                                              o_out, S_out, b_out);
}

// Round 2
// 1444.246 us; speedup vs baseline: 1.3270x; 1.3270x over previous
//
#include <hip/hip_runtime.h>

#define PFD 4   // prefetch distance (slots statically indexed via unrolled loop)

constexpr int Bv = 2, Tv = 4096, Hv = 8, Kv = 64, Vv = 64;

// sum over the 4 lanes of each quad via DPP quad_perm (VALU, no DS ops)
__device__ __forceinline__ float quad_sum(float x) {
    int t = __builtin_amdgcn_update_dpp(0, __float_as_int(x), 0xB1, 0xF, 0xF, true); // [1,0,3,2]
    x += __int_as_float(t);
    t = __builtin_amdgcn_update_dpp(0, __float_as_int(x), 0x4E, 0xF, 0xF, true);     // [2,3,0,1]
    x += __int_as_float(t);
    return x;
}

__global__ __launch_bounds__(64, 1)
void gdr1dc_kernel(const float* __restrict__ qg, const float* __restrict__ kg,
                   const float* __restrict__ vg, const float* __restrict__ gg,
                   const float* __restrict__ bg, const float* __restrict__ lqg,
                   const float* __restrict__ lkg, const float* __restrict__ S0,
                   const float* __restrict__ b0,
                   float* __restrict__ o_out, float* __restrict__ S_out,
                   float* __restrict__ b_out)
{
    const int bid  = blockIdx.x;
    const int bh   = bid >> 2;        // b*H + h
    const int cg   = bid & 3;         // group of 16 output columns
    const int lane = threadIdx.x;     // 0..63
    const int ksub = lane & 3;        // quad-local: which 16-slice of K
    const int col  = cg * 16 + (lane >> 2);   // output column v in [0,64)

    // state: this lane owns S[ksub*16 + j][col], j = 0..15
    float S[16];
#pragma unroll
    for (int j = 0; j < 16; ++j)
        S[j] = S0[((size_t)bh * Kv + (ksub * 16 + j)) * Vv + col];
    float bv = b0[(size_t)bh * Vv + col];   // replicated across the quad

    const int b = bh / Hv, h = bh % Hv;
    const size_t t0 = (size_t)b * Tv * Hv + h;   // flat [b,t=0,h] index
    const int HK = Hv * Kv, HV = Hv * Vv;

    // loop-carried load pointers (uniform -> SGPR), start at step 0
    const float* klp  = kg  + t0 * Kv;
    const float* qlp  = qg  + t0 * Kv;
    const float* vlp  = vg  + t0 * Vv;
    const float* glp  = gg  + t0;
    const float* blp  = bg  + t0;
    const float* lqlp = lqg + t0;
    const float* lklp = lkg + t0;
    float*       op   = o_out + t0 * Vv;

    float4 kr[PFD][4], qr[PFD][4];
    float  vr[PFD], gr[PFD], betr[PFD], lqr[PFD], lkr[PFD];

    // prologue: load steps 0..PFD-1; pointers end up at step PFD
#pragma unroll
    for (int p = 0; p < PFD; ++p) {
        const float4* k4 = (const float4*)(klp + ksub * 16);
        kr[p][0] = k4[0]; kr[p][1] = k4[1]; kr[p][2] = k4[2]; kr[p][3] = k4[3];
        const float4* q4 = (const float4*)(qlp + ksub * 16);
        qr[p][0] = q4[0]; qr[p][1] = q4[1]; qr[p][2] = q4[2]; qr[p][3] = q4[3];
        vr[p] = vlp[col];
        gr[p] = *glp; betr[p] = *blp; lqr[p] = *lqlp; lkr[p] = *lklp;
        klp += HK; qlp += HK; vlp += HV; glp += Hv; blp += Hv; lqlp += Hv; lklp += Hv;
    }

    for (int tt = 0; tt < Tv; tt += PFD) {
#pragma unroll
        for (int s = 0; s < PFD; ++s) {   // s compile-time after unroll
            const int t = tt + s;

            float ka[16], qa[16];
#pragma unroll
            for (int j = 0; j < 4; ++j) {
                ka[4*j+0] = kr[s][j].x; ka[4*j+1] = kr[s][j].y;
                ka[4*j+2] = kr[s][j].z; ka[4*j+3] = kr[s][j].w;
                qa[4*j+0] = qr[s][j].x; qa[4*j+1] = qr[s][j].y;
                qa[4*j+2] = qr[s][j].z; qa[4*j+3] = qr[s][j].w;
            }
            const float vt  = vr[s];
            const float dec = __expf(gr[s]);
            const float bt  = betr[s];
            const float lqt = lqr[s], lkt = lkr[s];

            // v_pred partial over this lane's 16 K-rows (4 independent chains)
            float a0 = 0.f, a1 = 0.f, a2 = 0.f, a3 = 0.f;
#pragma unroll
            for (int j = 0; j < 4; ++j) {
                a0 = fmaf(ka[4*j+0], S[4*j+0], a0);
                a1 = fmaf(ka[4*j+1], S[4*j+1], a1);
                a2 = fmaf(ka[4*j+2], S[4*j+2], a2);
                a3 = fmaf(ka[4*j+3], S[4*j+3], a3);
            }
            float vpred = quad_sum((a0 + a1) + (a2 + a3));   // reduce over quad (DPP)
            vpred = dec * fmaf(lkt, bv, vpred);              // = k·(dec·S) + lk·(dec·b)
            const float u = bt * (vt - vpred);

            // state update: S = dec*S + k⊗u (pre-decay folded)
#pragma unroll
            for (int j = 0; j < 16; ++j)
                S[j] = fmaf(ka[j], u, dec * S[j]);
            bv = fmaf(lkt, u, dec * bv);

            // output dot with updated state (off the recurrence critical path)
            float o0 = 0.f, o1 = 0.f, o2 = 0.f, o3 = 0.f;
#pragma unroll
            for (int j = 0; j < 4; ++j) {
                o0 = fmaf(qa[4*j+0], S[4*j+0], o0);
                o1 = fmaf(qa[4*j+1], S[4*j+1], o1);
                o2 = fmaf(qa[4*j+2], S[4*j+2], o2);
                o3 = fmaf(qa[4*j+3], S[4*j+3], o3);
            }
            float od = quad_sum((o0 + o1) + (o2 + o3));
            const float o = fmaf(0.125f, od, lqt * bv);
            if (ksub == 0)
                op[col] = o;
            op += HV;

            // prefetch step t+PFD into slot s (tail: re-load step Tv-1, unused)
            {
                const float4* k4 = (const float4*)(klp + ksub * 16);
                kr[s][0] = k4[0]; kr[s][1] = k4[1]; kr[s][2] = k4[2]; kr[s][3] = k4[3];
                const float4* q4 = (const float4*)(qlp + ksub * 16);
                qr[s][0] = q4[0]; qr[s][1] = q4[1]; qr[s][2] = q4[2]; qr[s][3] = q4[3];
                vr[s] = vlp[col];
                gr[s] = *glp; betr[s] = *blp; lqr[s] = *lqlp; lkr[s] = *lklp;
                if (t < Tv - 1 - PFD) {
                    klp += HK; qlp += HK; vlp += HV;
                    glp += Hv; blp += Hv; lqlp += Hv; lklp += Hv;
                }
            }
        }
    }

    // final state outputs
#pragma unroll
    for (int j = 0; j < 16; ++j)
        S_out[((size_t)bh * Kv + (ksub * 16 + j)) * Vv + col] = S[j];
    if (ksub == 0)
        b_out[(size_t)bh * Vv + col] = bv;
}

extern "C" void kernel_launch(void* const* d_in, const int* in_sizes, int n_in,
                              void* d_out, int out_size, void* d_ws, size_t ws_size,
                              hipStream_t stream) {
    const float* q   = (const float*)d_in[0];
    const float* k   = (const float*)d_in[1];
    const float* v   = (const float*)d_in[2];
    const float* g   = (const float*)d_in[3];
    const float* bet = (const float*)d_in[4];
    const float* lq  = (const float*)d_in[5];
    const float* lk  = (const float*)d_in[6];
    const float* S0  = (const float*)d_in[7];
    const float* b0  = (const float*)d_in[8];

    float* out   = (float*)d_out;
    float* o_out = out;
    float* S_out = out + (size_t)Bv * Tv * Hv * Vv;
    float* b_out = S_out + (size_t)Bv * Hv * Kv * Vv;

    dim3 grid(Bv * Hv * 4);   // (b,h) x 4 column-groups
    dim3 block(64);
    gdr1dc_kernel<<<grid, block, 0, stream>>>(q, k, v, g, bet, lq, lk, S0, b0,
                                              o_out, S_out, b_out);
}

// Round 3
// 929.984 us; speedup vs baseline: 2.0609x; 1.5530x over previous
//
#include <hip/hip_runtime.h>

#define PFD 8   // prefetch depth (statically indexed slots, unrolled x8)

constexpr int Bv = 2, Tv = 4096, Hv = 8, Kv = 64, Vv = 64;

// sum over the 4 lanes of each quad via DPP quad_perm (VALU, no DS ops)
__device__ __forceinline__ float quad_sum(float x) {
    int t = __builtin_amdgcn_update_dpp(0, __float_as_int(x), 0xB1, 0xF, 0xF, true); // [1,0,3,2]
    x += __int_as_float(t);
    t = __builtin_amdgcn_update_dpp(0, __float_as_int(x), 0x4E, 0xF, 0xF, true);     // [2,3,0,1]
    x += __int_as_float(t);
    return x;
}

// keep prefetch-slot registers live (defeats load sinking) without emitting code
#define PIN4(v4) asm volatile("" : "+v"((v4).x), "+v"((v4).y), "+v"((v4).z), "+v"((v4).w))

// One recurrence step. s_ = slot (compile-time), PF_ = 1 in main loop (pin + prefetch)
#define BODY(s_, PF_) do {                                                      \
    constexpr int s = (s_);                                                     \
    if (PF_) {  /* pin slot loaded 6 bodies ago, used 2 bodies from now */      \
        constexpr int p = (s + 2) & 7;                                          \
        PIN4(kr[p][0]); PIN4(kr[p][1]); PIN4(kr[p][2]); PIN4(kr[p][3]);         \
        PIN4(qr[p][0]); PIN4(qr[p][1]); PIN4(qr[p][2]); PIN4(qr[p][3]);         \
        asm volatile("" : "+v"(vr[p]), "+v"(gr[p]), "+v"(betr[p]),              \
                          "+v"(lqr[p]), "+v"(lkr[p]));                          \
    }                                                                           \
    const float dec = __expf(gr[s]);                                            \
    D *= dec;                                                                   \
    const float invD = __builtin_amdgcn_rcpf(D);                                \
    const float bvl  = lkr[s] * bv;        /* lam_k * b_reg   (off path) */     \
    const float bev  = betr[s] * vr[s];    /* beta * v        (off path) */     \
    float a0 = 0.f, a1 = 0.f, a2 = 0.f, a3 = 0.f;                               \
    _Pragma("unroll")                                                           \
    for (int j = 0; j < 4; ++j) {                                               \
        a0 = fmaf(kr[s][j].x, S[4*j+0], a0);                                    \
        a1 = fmaf(kr[s][j].y, S[4*j+1], a1);                                    \
        a2 = fmaf(kr[s][j].z, S[4*j+2], a2);                                    \
        a3 = fmaf(kr[s][j].w, S[4*j+3], a3);                                    \
    }                                                                           \
    const float dot   = quad_sum((a0 + a1) + (a2 + a3));                        \
    const float vpred = D * (dot + bvl);   /* = k.(dec S) + lk.(dec b) */       \
    const float u     = fmaf(-betr[s], vpred, bev);                             \
    const float us    = u * invD;                                               \
    _Pragma("unroll")                                                           \
    for (int j = 0; j < 4; ++j) {          /* S_reg += k * u/D : 16 FMA */      \
        S[4*j+0] = fmaf(kr[s][j].x, us, S[4*j+0]);                              \
        S[4*j+1] = fmaf(kr[s][j].y, us, S[4*j+1]);                              \
        S[4*j+2] = fmaf(kr[s][j].z, us, S[4*j+2]);                              \
        S[4*j+3] = fmaf(kr[s][j].w, us, S[4*j+3]);                              \
    }                                                                           \
    bv = fmaf(lkr[s], us, bv);                                                  \
    float o0 = 0.f, o1 = 0.f, o2 = 0.f, o3 = 0.f;                               \
    _Pragma("unroll")                                                           \
    for (int j = 0; j < 4; ++j) {                                               \
        o0 = fmaf(qr[s][j].x, S[4*j+0], o0);                                    \
        o1 = fmaf(qr[s][j].y, S[4*j+1], o1);                                    \
        o2 = fmaf(qr[s][j].z, S[4*j+2], o2);                                    \
        o3 = fmaf(qr[s][j].w, S[4*j+3], o3);                                    \
    }                                                                           \
    const float od = quad_sum((o0 + o1) + (o2 + o3));                           \
    op[col] = D * fmaf(0.125f, od, lqr[s] * bv);  /* 4 dup lanes, same value */ \
    op += HV;                                                                   \
    if (PF_) {  /* prefetch step t+PFD into slot s; pointers advance uncond. */ \
        const float4* k4 = (const float4*)(klp + (ksub << 4));                  \
        kr[s][0] = k4[0]; kr[s][1] = k4[1]; kr[s][2] = k4[2]; kr[s][3] = k4[3]; \
        const float4* q4 = (const float4*)(qlp + (ksub << 4));                  \
        qr[s][0] = q4[0]; qr[s][1] = q4[1]; qr[s][2] = q4[2]; qr[s][3] = q4[3]; \
        vr[s] = vlp[col];                                                       \
        gr[s] = *glp; betr[s] = *blp; lqr[s] = *lqlp; lkr[s] = *lklp;           \
        klp += HK; qlp += HK; vlp += HV;                                        \
        glp += Hv; blp += Hv; lqlp += Hv; lklp += Hv;                           \
    }                                                                           \
} while (0)

__global__ __launch_bounds__(64, 1)
void gdr1dc_kernel(const float* __restrict__ qg, const float* __restrict__ kg,
                   const float* __restrict__ vg, const float* __restrict__ gg,
                   const float* __restrict__ bg, const float* __restrict__ lqg,
                   const float* __restrict__ lkg, const float* __restrict__ S0,
                   const float* __restrict__ b0,
                   float* __restrict__ o_out, float* __restrict__ S_out,
                   float* __restrict__ b_out)
{
    const int bid  = blockIdx.x;
    const int bh   = bid & 15;        // b*H + h  (XCD swizzle: the 4 column-group
    const int cg   = bid >> 4;        //  blocks of one bh land on the same XCD)
    const int lane = threadIdx.x;     // 0..63
    const int ksub = lane & 3;        // quad-local: which 16-slice of K
    const int col  = cg * 16 + (lane >> 2);   // output column v in [0,64)

    // state: this lane owns S[ksub*16 + j][col]; kept as S_true = D * S_reg
    float S[16];
#pragma unroll
    for (int j = 0; j < 16; ++j)
        S[j] = S0[((size_t)bh * Kv + (ksub * 16 + j)) * Vv + col];
    float bv = b0[(size_t)bh * Vv + col];   // replicated across the quad
    float D  = 1.0f;                        // running decay product (rescaled)

    const int b = bh / Hv, h = bh % Hv;
    const size_t t0 = (size_t)b * Tv * Hv + h;   // flat [b,t=0,h] index
    const int HK = Hv * Kv, HV = Hv * Vv;

    const float* klp  = kg  + t0 * Kv;
    const float* qlp  = qg  + t0 * Kv;
    const float* vlp  = vg  + t0 * Vv;
    const float* glp  = gg  + t0;
    const float* blp  = bg  + t0;
    const float* lqlp = lqg + t0;
    const float* lklp = lkg + t0;
    float*       op   = o_out + t0 * Vv;

    float4 kr[PFD][4], qr[PFD][4];
    float  vr[PFD], gr[PFD], betr[PFD], lqr[PFD], lkr[PFD];

    // prologue: slots 0..7 <- steps 0..7; pointers end at step 8
#pragma unroll
    for (int p = 0; p < PFD; ++p) {
        const float4* k4 = (const float4*)(klp + (ksub << 4));
        kr[p][0] = k4[0]; kr[p][1] = k4[1]; kr[p][2] = k4[2]; kr[p][3] = k4[3];
        const float4* q4 = (const float4*)(qlp + (ksub << 4));
        qr[p][0] = q4[0]; qr[p][1] = q4[1]; qr[p][2] = q4[2]; qr[p][3] = q4[3];
        vr[p] = vlp[col];
        gr[p] = *glp; betr[p] = *blp; lqr[p] = *lqlp; lkr[p] = *lklp;
        klp += HK; qlp += HK; vlp += HV; glp += Hv; blp += Hv; lqlp += Hv; lklp += Hv;
    }

    // main loop: 511 groups of 8 steps, unconditional prefetch (always in-bounds)
    for (int tt = 0; tt < Tv - PFD; tt += PFD) {
        if ((tt & 31) == 0 && tt) {   // rescale every 32 steps: |1/D| <= e^32
#pragma unroll
            for (int j = 0; j < 16; ++j) S[j] *= D;
            bv *= D; D = 1.0f;
        }
        BODY(0, 1); BODY(1, 1); BODY(2, 1); BODY(3, 1);
        BODY(4, 1); BODY(5, 1); BODY(6, 1); BODY(7, 1);
    }
    // epilogue: last 8 steps, no prefetch
    BODY(0, 0); BODY(1, 0); BODY(2, 0); BODY(3, 0);
    BODY(4, 0); BODY(5, 0); BODY(6, 0); BODY(7, 0);

    // final state outputs (un-scale)
#pragma unroll
    for (int j = 0; j < 16; ++j)
        S_out[((size_t)bh * Kv + (ksub * 16 + j)) * Vv + col] = D * S[j];
    b_out[(size_t)bh * Vv + col] = D * bv;   // 4 dup lanes, same value
}

extern "C" void kernel_launch(void* const* d_in, const int* in_sizes, int n_in,
                              void* d_out, int out_size, void* d_ws, size_t ws_size,
                              hipStream_t stream) {
    const float* q   = (const float*)d_in[0];
    const float* k   = (const float*)d_in[1];
    const float* v   = (const float*)d_in[2];
    const float* g   = (const float*)d_in[3];
    const float* bet = (const float*)d_in[4];
    const float* lq  = (const float*)d_in[5];
    const float* lk  = (const float*)d_in[6];
    const float* S0  = (const float*)d_in[7];
    const float* b0  = (const float*)d_in[8];

    float* out   = (float*)d_out;
    float* o_out = out;
    float* S_out = out + (size_t)Bv * Tv * Hv * Vv;
    float* b_out = S_out + (size_t)Bv * Hv * Kv * Vv;

    dim3 grid(Bv * Hv * 4);   // (b,h) x 4 column-groups
    dim3 block(64);
    gdr1dc_kernel<<<grid, block, 0, stream>>>(q, k, v, g, bet, lq, lk, S0, b0,
                                              o_out, S_out, b_out);
}

// Round 4
// 505.130 us; speedup vs baseline: 3.7942x; 1.8411x over previous
//
#include <hip/hip_runtime.h>

#define PFD 8   // prefetch depth (statically indexed slots, unrolled x8)

constexpr int Bv = 2, Tv = 4096, Hv = 8, Kv = 64, Vv = 64;

// full sum over each contiguous 16-lane row via DPP (VALU only, no DS ops)
__device__ __forceinline__ float row16_sum(float x) {
    int t;
    t = __builtin_amdgcn_update_dpp(0, __float_as_int(x), 0x128, 0xF, 0xF, true); // row_ror:8
    x += __int_as_float(t);
    t = __builtin_amdgcn_update_dpp(0, __float_as_int(x), 0x124, 0xF, 0xF, true); // row_ror:4
    x += __int_as_float(t);
    t = __builtin_amdgcn_update_dpp(0, __float_as_int(x), 0x4E, 0xF, 0xF, true);  // quad_perm [2,3,0,1]
    x += __int_as_float(t);
    t = __builtin_amdgcn_update_dpp(0, __float_as_int(x), 0xB1, 0xF, 0xF, true);  // quad_perm [1,0,3,2]
    x += __int_as_float(t);
    return x;
}

// keep prefetch-slot registers live (defeats load sinking) without emitting code
#define PIN4(v4) asm volatile("" : "+v"((v4).x), "+v"((v4).y), "+v"((v4).z), "+v"((v4).w))

// One recurrence step. s_ = slot (compile-time), PF_ = 1 in main loop (pin + prefetch)
#define BODY(s_, PF_) do {                                                      \
    constexpr int s = (s_);                                                     \
    if (PF_) {  /* pin slot loaded 5 bodies ago, used 3 bodies from now */      \
        constexpr int p = (s + 3) & 7;                                          \
        PIN4(kr[p]); PIN4(qr[p]);                                               \
        asm volatile("" : "+v"(vr[p]));                                         \
    }                                                                           \
    const float dec = __expf(gr[s]);                                            \
    D *= dec;                                                                   \
    const float invD = __builtin_amdgcn_rcpf(D);                                \
    const float bvl  = lkr[s] * bv;        /* lam_k * b_reg   (off path) */     \
    const float bev  = betr[s] * vr[s];    /* beta * v        (off path) */     \
    float a0 = kr[s].x * S[0], a1 = kr[s].y * S[1];                             \
    a0 = fmaf(kr[s].z, S[2], a0); a1 = fmaf(kr[s].w, S[3], a1);                 \
    const float dot   = row16_sum(a0 + a1);                                     \
    const float vpred = D * (dot + bvl);   /* = k.(dec S) + lk.(dec b) */       \
    const float u     = fmaf(-betr[s], vpred, bev);                             \
    const float us    = u * invD;                                               \
    S[0] = fmaf(kr[s].x, us, S[0]); S[1] = fmaf(kr[s].y, us, S[1]);             \
    S[2] = fmaf(kr[s].z, us, S[2]); S[3] = fmaf(kr[s].w, us, S[3]);             \
    bv = fmaf(lkr[s], us, bv);                                                  \
    float o0 = qr[s].x * S[0], o1 = qr[s].y * S[1];                             \
    o0 = fmaf(qr[s].z, S[2], o0); o1 = fmaf(qr[s].w, S[3], o1);                 \
    const float od = row16_sum(o0 + o1);                                        \
    op[col] = D * fmaf(0.125f, od, lqr[s] * bv);  /* 16 dup lanes, same val */  \
    op += HV;                                                                   \
    if (PF_) {  /* prefetch step t+PFD into slot s */                           \
        kr[s] = *(const float4*)(klp + (ksub << 2));                            \
        qr[s] = *(const float4*)(qlp + (ksub << 2));                            \
        vr[s] = vlp[col];                                                       \
        gr[s] = *glp; betr[s] = *blp; lqr[s] = *lqlp; lkr[s] = *lklp;           \
        klp += HK; qlp += HK; vlp += HV;                                        \
        glp += Hv; blp += Hv; lqlp += Hv; lklp += Hv;                           \
    }                                                                           \
} while (0)

__global__ __launch_bounds__(64, 1)
void gdr1dc_kernel(const float* __restrict__ qg, const float* __restrict__ kg,
                   const float* __restrict__ vg, const float* __restrict__ gg,
                   const float* __restrict__ bg, const float* __restrict__ lqg,
                   const float* __restrict__ lkg, const float* __restrict__ S0,
                   const float* __restrict__ b0,
                   float* __restrict__ o_out, float* __restrict__ S_out,
                   float* __restrict__ b_out)
{
    const int bid  = blockIdx.x;
    // XCD swizzle: bid%8 = XCD (round-robin dispatch). Keep all 16 column-group
    // blocks of one (b,h) on one XCD so they share k/q in that XCD's L2.
    const int slot = bid >> 3;                    // 0..31
    const int bh   = (bid & 7) + 8 * (slot >> 4); // b*H + h
    const int cg   = slot & 15;                   // column group (4 cols each)
    const int lane = threadIdx.x;                 // 0..63
    const int ksub = lane & 15;                   // which 4-slice of K
    const int col  = cg * 4 + (lane >> 4);        // output column v in [0,64)

    // state: this lane owns S[ksub*4 + j][col]; kept as S_true = D * S_reg
    float S[4];
#pragma unroll
    for (int j = 0; j < 4; ++j)
        S[j] = S0[((size_t)bh * Kv + (ksub * 4 + j)) * Vv + col];
    float bv = b0[(size_t)bh * Vv + col];   // replicated across the 16 row-lanes
    float D  = 1.0f;                        // running decay product (rescaled)

    const int b = bh / Hv, h = bh % Hv;
    const size_t t0 = (size_t)b * Tv * Hv + h;   // flat [b,t=0,h] index
    const int HK = Hv * Kv, HV = Hv * Vv;

    const float* klp  = kg  + t0 * Kv;
    const float* qlp  = qg  + t0 * Kv;
    const float* vlp  = vg  + t0 * Vv;
    const float* glp  = gg  + t0;
    const float* blp  = bg  + t0;
    const float* lqlp = lqg + t0;
    const float* lklp = lkg + t0;
    float*       op   = o_out + t0 * Vv;

    float4 kr[PFD], qr[PFD];
    float  vr[PFD], gr[PFD], betr[PFD], lqr[PFD], lkr[PFD];

    // prologue: slots 0..7 <- steps 0..7; pointers end at step 8
#pragma unroll
    for (int p = 0; p < PFD; ++p) {
        kr[p] = *(const float4*)(klp + (ksub << 2));
        qr[p] = *(const float4*)(qlp + (ksub << 2));
        vr[p] = vlp[col];
        gr[p] = *glp; betr[p] = *blp; lqr[p] = *lqlp; lkr[p] = *lklp;
        klp += HK; qlp += HK; vlp += HV; glp += Hv; blp += Hv; lqlp += Hv; lklp += Hv;
    }

    // main loop: 511 groups of 8 steps, unconditional in-bounds prefetch
    for (int tt = 0; tt < Tv - PFD; tt += PFD) {
        if ((tt & 31) == 0 && tt) {   // rescale every 32 steps: |1/D| <= e^32
#pragma unroll
            for (int j = 0; j < 4; ++j) S[j] *= D;
            bv *= D; D = 1.0f;
        }
        BODY(0, 1); BODY(1, 1); BODY(2, 1); BODY(3, 1);
        BODY(4, 1); BODY(5, 1); BODY(6, 1); BODY(7, 1);
    }
    // epilogue: last 8 steps, no prefetch
    BODY(0, 0); BODY(1, 0); BODY(2, 0); BODY(3, 0);
    BODY(4, 0); BODY(5, 0); BODY(6, 0); BODY(7, 0);

    // final state outputs (un-scale)
#pragma unroll
    for (int j = 0; j < 4; ++j)
        S_out[((size_t)bh * Kv + (ksub * 4 + j)) * Vv + col] = D * S[j];
    b_out[(size_t)bh * Vv + col] = D * bv;   // dup lanes, same value
}

extern "C" void kernel_launch(void* const* d_in, const int* in_sizes, int n_in,
                              void* d_out, int out_size, void* d_ws, size_t ws_size,
                              hipStream_t stream) {
    const float* q   = (const float*)d_in[0];
    const float* k   = (const float*)d_in[1];
    const float* v   = (const float*)d_in[2];
    const float* g   = (const float*)d_in[3];
    const float* bet = (const float*)d_in[4];
    const float* lq  = (const float*)d_in[5];
    const float* lk  = (const float*)d_in[6];
    const float* S0  = (const float*)d_in[7];
    const float* b0  = (const float*)d_in[8];

    float* out   = (float*)d_out;
    float* o_out = out;
    float* S_out = out + (size_t)Bv * Tv * Hv * Vv;
    float* b_out = S_out + (size_t)Bv * Hv * Kv * Vv;

    dim3 grid(Bv * Hv * 16);   // (b,h) x 16 column-groups = 256 blocks (1/CU)
    dim3 block(64);
    gdr1dc_kernel<<<grid, block, 0, stream>>>(q, k, v, g, bet, lq, lk, S0, b0,
                                              o_out, S_out, b_out);
}